// Round 7
// baseline (191.227 us; speedup 1.0000x reference)
//
#include <hip/hip_runtime.h>
#include <hip/hip_cooperative_groups.h>
#include <math.h>

namespace cg = cooperative_groups;

// Problem constants
#define BATCH 16
#define CIN 32
#define COUT 96
#define WH 64
#define IMG (WH*WH)              // 4096
#define NPIX (BATCH*IMG)         // 65536 per channel
#define YELEMS (BATCH*COUT*IMG)  // 6291456
#define NPART 128                // partials per channel: 16 b * 8 rowg
#define PWELEMS (3*9*32*32)      // 27648 packed bf16 weights
#define XTELEMS (BATCH*IMG*CIN)  // 2097152 bf16 transposed x

typedef __attribute__((ext_vector_type(8))) short short8;
typedef __attribute__((ext_vector_type(4))) float floatx4;

__device__ __forceinline__ unsigned short f2bf(float f) {
    union { float f; unsigned u; } v; v.f = f;
    unsigned r = v.u + 0x7FFFu + ((v.u >> 16) & 1u);  // RNE
    return (unsigned short)(r >> 16);
}

#define GLDS(src, dst) __builtin_amdgcn_global_load_lds( \
    (const __attribute__((address_space(1))) void*)(src), \
    (__attribute__((address_space(3))) void*)(dst), 16, 0, 0)

__device__ __forceinline__ float fast_tanh(float xv) {
    float e = __expf(2.0f * xv);
    return fmaf(-2.0f, __builtin_amdgcn_rcpf(e + 1.0f), 1.0f);
}

// ---------------------------------------------------------------------------
// prep: blocks 0..255 transpose x -> xT[b][pix][c] bf16 ; blocks 256..363 pack
// weights -> pw[cfg][tap][oc32][c32] bf16. Both live in d_out's front 4.2 MB.
// ---------------------------------------------------------------------------
__global__ __launch_bounds__(256) void prep_kernel(
    const float* __restrict__ x, const float* __restrict__ w,
    unsigned short* __restrict__ xT, unsigned short* __restrict__ pw)
{
    int blk = blockIdx.x;
    if (blk < 256) {
        int t   = blk * 256 + threadIdx.x;   // 65536 = 16 b * 4096 pix
        int b   = t >> 12;
        int pix = t & 4095;
        const float* xb = x + (size_t)b * CIN * IMG + pix;
        unsigned packed[16];
#pragma unroll
        for (int c2 = 0; c2 < 16; c2++) {
            unsigned short lo = f2bf(xb[(size_t)(2 * c2) * IMG]);
            unsigned short hi = f2bf(xb[(size_t)(2 * c2 + 1) * IMG]);
            packed[c2] = (unsigned)lo | ((unsigned)hi << 16);
        }
        uint4* dst = (uint4*)(xT + (size_t)t * 32);
#pragma unroll
        for (int k = 0; k < 4; k++)
            dst[k] = make_uint4(packed[4 * k], packed[4 * k + 1],
                                packed[4 * k + 2], packed[4 * k + 3]);
    } else {
        int e = (blk - 256) * 256 + threadIdx.x;
        if (e >= PWELEMS) return;
        int cfg = e / (9 * 1024);
        int rem = e % (9 * 1024);
        int tap = rem >> 10;
        int oc  = (rem >> 5) & 31;
        int c   = rem & 31;
        int d   = cfg + 1;
        int du  = tap / 3, dv = tap % 3;
        size_t idx = (((size_t)(cfg * 32 + oc) * CIN + c) * 65 + (32 + (du - 1) * d)) * 65
                     + (32 + (dv - 1) * d);
        pw[e] = f2bf(w[idx]);
    }
}

// ---------------------------------------------------------------------------
// Shared conv body (implicit GEMM, MFMA 16x16x32 bf16). Block covers
// 32 oc x 8 rows x 64 cols; wave = 2 rows; per thread 64 outputs in regs.
// ---------------------------------------------------------------------------
struct ConvCtx {
    int cfg, b, i0, d;
    int t, wv, lane, l15, quad;
};

__device__ __forceinline__ void conv_compute(
    const ConvCtx& C, const unsigned short* __restrict__ xT,
    const unsigned short* __restrict__ pw, unsigned short* tile,
    float (*red_s)[32], float (*red_q)[32],
    float* __restrict__ psum, float* __restrict__ psq,
    floatx4 acc[2][4][2])
{
    // stage 14 rows (i0-3 .. i0+10, circular) x 64 cols x 32 ch bf16 = 57344 B
    const unsigned short* xTb = xT + (size_t)C.b * IMG * 32;
#pragma unroll
    for (int rr = 0; rr < 14; rr++) {
        int gi = (C.i0 - 3 + rr) & 63;
        GLDS(xTb + (size_t)gi * 2048 + C.t * 8, &tile[rr * 2048 + C.t * 8]);
    }

    // A-frags: lane l holds w[oc = h*16 + l15][c = quad*8 .. +8] per tap
    const unsigned short* pwc = pw + (size_t)C.cfg * 9 * 32 * 32;
    short8 af[2][9];
#pragma unroll
    for (int h = 0; h < 2; h++)
#pragma unroll
        for (int tap = 0; tap < 9; tap++)
            af[h][tap] = *(const short8*)(pwc + ((tap * 32 + h * 16 + C.l15) * 32 + C.quad * 8));

    __syncthreads();  // drains GLDS (vmcnt) for all waves

#pragma unroll 1
    for (int cg = 0; cg < 4; cg++) {
#pragma unroll
        for (int r = 0; r < 2; r++) {
            floatx4 a0 = {0.f, 0.f, 0.f, 0.f};
            floatx4 a1 = {0.f, 0.f, 0.f, 0.f};
#pragma unroll
            for (int du = 0; du < 3; du++) {
                int rowloc = 2 * C.wv + r + 3 + (du - 1) * C.d;   // 0..13
                const unsigned short* rbase = &tile[rowloc * 2048 + C.quad * 8];
#pragma unroll
                for (int dv = 0; dv < 3; dv++) {
                    int col = (cg * 16 + C.l15 + (dv - 1) * C.d) & 63;
                    short8 bf = *(const short8*)(rbase + col * 32);
                    a0 = __builtin_amdgcn_mfma_f32_16x16x32_bf16(af[0][du * 3 + dv], bf, a0, 0, 0, 0);
                    a1 = __builtin_amdgcn_mfma_f32_16x16x32_bf16(af[1][du * 3 + dv], bf, a1, 0, 0, 0);
                }
            }
            acc[r][cg][0] = a0;
            acc[r][cg][1] = a1;
        }
    }

    // stats from held accumulators
    float ss[2][4], qq[2][4];
#pragma unroll
    for (int h = 0; h < 2; h++)
#pragma unroll
        for (int reg = 0; reg < 4; reg++) { ss[h][reg] = 0.f; qq[h][reg] = 0.f; }
#pragma unroll
    for (int r = 0; r < 2; r++)
#pragma unroll
        for (int cg = 0; cg < 4; cg++)
#pragma unroll
            for (int h = 0; h < 2; h++)
#pragma unroll
                for (int reg = 0; reg < 4; reg++) {
                    float v = acc[r][cg][h][reg];
                    ss[h][reg] += v;
                    qq[h][reg] = fmaf(v, v, qq[h][reg]);
                }
#pragma unroll
    for (int h = 0; h < 2; h++)
#pragma unroll
        for (int reg = 0; reg < 4; reg++) {
            float s = ss[h][reg], q = qq[h][reg];
            for (int m = 1; m < 16; m <<= 1) {
                s += __shfl_xor(s, m, 64);
                q += __shfl_xor(q, m, 64);
            }
            if (C.l15 == 0) {
                red_s[C.wv][h * 16 + C.quad * 4 + reg] = s;
                red_q[C.wv][h * 16 + C.quad * 4 + reg] = q;
            }
        }
    __syncthreads();
    int t = C.t;
    int rowg = C.i0 >> 3;
    if (t < 32) {
        float S = red_s[0][t] + red_s[1][t] + red_s[2][t] + red_s[3][t];
        psum[(size_t)(C.cfg * 32 + t) * NPART + C.b * 8 + rowg] = S;
    } else if (t < 64) {
        int o = t - 32;
        float Q = red_q[0][o] + red_q[1][o] + red_q[2][o] + red_q[3][o];
        psq[(size_t)(C.cfg * 32 + o) * NPART + C.b * 8 + rowg] = Q;
    }
}

__device__ __forceinline__ ConvCtx make_ctx(int bid, int t) {
    ConvCtx C;
    int rowg = bid & 7;
    int rest = bid >> 3;          // 0..47
    C.cfg = rest % 3;
    C.b   = rest / 3;
    C.d   = C.cfg + 1;
    C.i0  = rowg * 8;
    C.t   = t;
    C.wv  = t >> 6;
    C.lane = t & 63;
    C.l15 = C.lane & 15;
    C.quad = C.lane >> 4;
    return C;
}

// ---------------------------------------------------------------------------
// COOPERATIVE fused path: conv + stats + grid sync + BN + tanh. grid 384.
// All reads of xT/pw (aliasing d_out) happen pre-sync; out writes post-sync.
// ---------------------------------------------------------------------------
__global__ __launch_bounds__(256, 2) void conv_fused_kernel(
    const unsigned short* __restrict__ xT, const unsigned short* __restrict__ pw,
    float* __restrict__ psum, float* __restrict__ psq,
    const float* __restrict__ gamma, const float* __restrict__ beta,
    float* __restrict__ out)
{
    __shared__ __align__(16) unsigned short tile[14 * 2048];
    __shared__ float red_s[4][32];
    __shared__ float red_q[4][32];
    __shared__ float sc_a[32], sc_b[32];

    ConvCtx C = make_ctx(blockIdx.x, threadIdx.x);
    floatx4 acc[2][4][2];
    conv_compute(C, xT, pw, tile, red_s, red_q, psum, psq, acc);

    cg::this_grid().sync();  // all psum/psq written; all xT/pw reads done

    // finalize BN params for this block's 32 channels (redundant, L2-hot)
    {
        int chl   = C.t >> 3;        // 0..31
        int slice = C.t & 7;         // 8 slices of 16 partials
        const float* ps = psum + (size_t)(C.cfg * 32 + chl) * NPART + slice * 16;
        const float* pq = psq  + (size_t)(C.cfg * 32 + chl) * NPART + slice * 16;
        float s = 0.f, q = 0.f;
#pragma unroll
        for (int k = 0; k < 16; k++) { s += ps[k]; q += pq[k]; }
        for (int m = 1; m < 8; m <<= 1) {
            s += __shfl_xor(s, m, 8);
            q += __shfl_xor(q, m, 8);
        }
        if (slice == 0) {
            const float inv_n = 1.0f / (float)NPIX;
            float mean = s * inv_n;
            float var  = q * inv_n - mean * mean;
            float a    = gamma[C.cfg * 32 + chl] * rsqrtf(var + 1e-5f);
            sc_a[chl] = a;
            sc_b[chl] = beta[C.cfg * 32 + chl] - mean * a;
        }
    }
    __syncthreads();

    // epilogue: BN + tanh on held registers, write out
#pragma unroll
    for (int r = 0; r < 2; r++) {
        int row = C.i0 + 2 * C.wv + r;
        size_t obase = ((size_t)C.b * COUT + C.cfg * 32) * IMG + (size_t)row * WH;
#pragma unroll
        for (int cg = 0; cg < 4; cg++) {
            int colg = cg * 16 + C.l15;
#pragma unroll
            for (int h = 0; h < 2; h++)
#pragma unroll
                for (int reg = 0; reg < 4; reg++) {
                    int oc = h * 16 + C.quad * 4 + reg;
                    float v = fmaf(acc[r][cg][h][reg], sc_a[oc], sc_b[oc]);
                    out[obase + (size_t)oc * IMG + colg] = fast_tanh(v);
                }
        }
    }
}

// ---------------------------------------------------------------------------
// FALLBACK split path (validated R5 structure): conv writes y to ws, then
// bn_tanh finalizes. Used only if cooperative co-residency isn't available.
// ---------------------------------------------------------------------------
__global__ __launch_bounds__(256, 2) void conv_split_kernel(
    const unsigned short* __restrict__ xT, const unsigned short* __restrict__ pw,
    float* __restrict__ y, float* __restrict__ psum, float* __restrict__ psq)
{
    __shared__ __align__(16) unsigned short tile[14 * 2048];
    __shared__ float red_s[4][32];
    __shared__ float red_q[4][32];

    ConvCtx C = make_ctx(blockIdx.x, threadIdx.x);
    floatx4 acc[2][4][2];
    conv_compute(C, xT, pw, tile, red_s, red_q, psum, psq, acc);

#pragma unroll
    for (int r = 0; r < 2; r++) {
        int row = C.i0 + 2 * C.wv + r;
        size_t ybase = ((size_t)C.b * COUT + C.cfg * 32) * IMG + (size_t)row * WH;
#pragma unroll
        for (int cg = 0; cg < 4; cg++) {
            int colg = cg * 16 + C.l15;
#pragma unroll
            for (int h = 0; h < 2; h++)
#pragma unroll
                for (int reg = 0; reg < 4; reg++) {
                    int oc = h * 16 + C.quad * 4 + reg;
                    y[ybase + (size_t)oc * IMG + colg] = acc[r][cg][h][reg];
                }
        }
    }
}

__global__ __launch_bounds__(256) void bn_tanh_kernel(
    const float* __restrict__ ybuf, const float* __restrict__ psum,
    const float* __restrict__ psq, const float* __restrict__ gamma,
    const float* __restrict__ beta, float* __restrict__ out)
{
    __shared__ float part[4];
    __shared__ float sc[2];
    int t  = threadIdx.x;
    int ch = blockIdx.x % COUT;

    float s = 0.f, q = 0.f;
    if (t < NPART) { s = psum[(size_t)ch * NPART + t]; q = psq[(size_t)ch * NPART + t]; }
    for (int m = 1; m < 64; m <<= 1) {
        s += __shfl_xor(s, m, 64);
        q += __shfl_xor(q, m, 64);
    }
    if (t < NPART && (t & 63) == 0) { part[t >> 6] = s; part[2 + (t >> 6)] = q; }
    __syncthreads();
    if (t == 0) {
        const float inv_n = 1.0f / (float)NPIX;
        float S = part[0] + part[1], Q = part[2] + part[3];
        float mean = S * inv_n;
        float var  = Q * inv_n - mean * mean;
        float a    = gamma[ch] * rsqrtf(var + 1e-5f);
        sc[0] = a;
        sc[1] = beta[ch] - mean * a;
    }
    __syncthreads();

    float a = sc[0], bsh = sc[1];
    size_t base4 = (size_t)blockIdx.x * 1024;  // float4 units
#pragma unroll
    for (int k = 0; k < 4; k++) {
        size_t e4 = base4 + k * 256 + t;
        float4 v = ((const float4*)ybuf)[e4];
        float4 r;
        r.x = fast_tanh(fmaf(v.x, a, bsh));
        r.y = fast_tanh(fmaf(v.y, a, bsh));
        r.z = fast_tanh(fmaf(v.z, a, bsh));
        r.w = fast_tanh(fmaf(v.w, a, bsh));
        ((float4*)out)[e4] = r;
    }
}

extern "C" void kernel_launch(void* const* d_in, const int* in_sizes, int n_in,
                              void* d_out, int out_size, void* d_ws, size_t ws_size,
                              hipStream_t stream) {
    const float* x     = (const float*)d_in[0];
    const float* w     = (const float*)d_in[1];
    // d_in[2] = mask: tap positions known analytically (3x3 dilated, centered at 32)
    const float* gamma = (const float*)d_in[3];
    const float* beta  = (const float*)d_in[4];
    float* out = (float*)d_out;

    float* ws   = (float*)d_ws;
    float* psum = ws;                        // 96*128
    float* psq  = psum + COUT * NPART;       // 96*128
    float* ybuf = psq + COUT * NPART;        // 6291456 floats (fallback only)

    // xT (4 MB) + pw (54 KB) live in d_out's front; conv reads them only
    // before the grid sync / in the split conv, writes out only after.
    unsigned short* xT = (unsigned short*)d_out;            // 2097152 bf16
    unsigned short* pw = xT + XTELEMS;                      // 27648 bf16

    prep_kernel<<<256 + (PWELEMS + 255) / 256, 256, 0, stream>>>(x, w, xT, pw);

    // deterministic host-side query (capture-safe): can 384 blocks co-reside?
    int blocksPerCU = 0;
    hipError_t qe = hipOccupancyMaxActiveBlocksPerMultiprocessor(
        &blocksPerCU, (const void*)conv_fused_kernel, 256, 0);
    bool coop_ok = (qe == hipSuccess) && ((long)blocksPerCU * 256 >= 384);

    if (coop_ok) {
        void* args[] = {(void*)&xT, (void*)&pw, (void*)&psum, (void*)&psq,
                        (void*)&gamma, (void*)&beta, (void*)&out};
        hipError_t le = hipLaunchCooperativeKernel((const void*)conv_fused_kernel,
                                                   dim3(384), dim3(256), args, 0, stream);
        if (le == hipSuccess) return;
        // fall through to split path if the enqueue itself was rejected
    }

    conv_split_kernel<<<384, 256, 0, stream>>>(xT, pw, ybuf, psum, psq);
    bn_tanh_kernel<<<BATCH * COUT, 256, 0, stream>>>(ybuf, psum, psq, gamma, beta, out);
}

// Round 8
// 123.197 us; speedup vs baseline: 1.5522x; 1.5522x over previous
//
#include <hip/hip_runtime.h>
#include <math.h>

// Problem constants
#define BATCH 16
#define CIN 32
#define COUT 96
#define WH 64
#define IMG (WH*WH)              // 4096
#define NPIX (BATCH*IMG)         // 65536 per channel
#define NPART 256                // partials per channel: 16 b * 16 rowg
#define PWELEMS (3*9*32*32)      // 27648 packed bf16 weights
#define XTELEMS (BATCH*IMG*CIN)  // 2097152 bf16 transposed x

typedef __attribute__((ext_vector_type(8))) short short8;
typedef __attribute__((ext_vector_type(4))) float floatx4;

__device__ __forceinline__ unsigned short f2bf(float f) {
    union { float f; unsigned u; } v; v.f = f;
    unsigned r = v.u + 0x7FFFu + ((v.u >> 16) & 1u);  // RNE
    return (unsigned short)(r >> 16);
}

#define GLDS(src, dst) __builtin_amdgcn_global_load_lds( \
    (const __attribute__((address_space(1))) void*)(src), \
    (__attribute__((address_space(3))) void*)(dst), 16, 0, 0)

__device__ __forceinline__ float fast_tanh(float xv) {
    float e = __expf(2.0f * xv);
    return fmaf(-2.0f, __builtin_amdgcn_rcpf(e + 1.0f), 1.0f);
}

// ---------------------------------------------------------------------------
// prep: blocks 0..255 transpose x -> xT[b][pix][c] bf16 ; blocks 256.. pack
// weights -> pw[cfg][tap][oc32][c32] bf16. Both live in d_ws (no aliasing).
// ---------------------------------------------------------------------------
__global__ __launch_bounds__(256) void prep_kernel(
    const float* __restrict__ x, const float* __restrict__ w,
    unsigned short* __restrict__ xT, unsigned short* __restrict__ pw)
{
    int blk = blockIdx.x;
    if (blk < 256) {
        int t   = blk * 256 + threadIdx.x;   // 65536 = 16 b * 4096 pix
        int b   = t >> 12;
        int pix = t & 4095;
        const float* xb = x + (size_t)b * CIN * IMG + pix;
        unsigned packed[16];
#pragma unroll
        for (int c2 = 0; c2 < 16; c2++) {
            unsigned short lo = f2bf(xb[(size_t)(2 * c2) * IMG]);
            unsigned short hi = f2bf(xb[(size_t)(2 * c2 + 1) * IMG]);
            packed[c2] = (unsigned)lo | ((unsigned)hi << 16);
        }
        uint4* dst = (uint4*)(xT + (size_t)t * 32);
#pragma unroll
        for (int k = 0; k < 4; k++)
            dst[k] = make_uint4(packed[4 * k], packed[4 * k + 1],
                                packed[4 * k + 2], packed[4 * k + 3]);
    } else {
        int e = (blk - 256) * 256 + threadIdx.x;
        if (e >= PWELEMS) return;
        int cfg = e / (9 * 1024);
        int rem = e % (9 * 1024);
        int tap = rem >> 10;
        int oc  = (rem >> 5) & 31;
        int c   = rem & 31;
        int d   = cfg + 1;
        int du  = tap / 3, dv = tap % 3;
        size_t idx = (((size_t)(cfg * 32 + oc) * CIN + c) * 65 + (32 + (du - 1) * d)) * 65
                     + (32 + (dv - 1) * d);
        pw[e] = f2bf(w[idx]);
    }
}

// ---------------------------------------------------------------------------
// Pass 1: conv (implicit GEMM, MFMA 16x16x32 bf16) -> per-block stats ONLY.
// grid = 16 b * 3 cfg * 16 rowg = 768 ; block 256 (4 waves) ; 3 blk/CU.
// Block: 32 oc x 4 rows x 64 cols. No y write — y is recomputed in pass 2.
// ---------------------------------------------------------------------------
__global__ __launch_bounds__(256, 3) void conv_stats_kernel(
    const unsigned short* __restrict__ xT, const unsigned short* __restrict__ pw,
    float* __restrict__ psum, float* __restrict__ psq)
{
    int bid  = blockIdx.x;
    int rowg = bid & 15;
    int rest = bid >> 4;         // 0..47
    int cfg  = rest % 3;
    int b    = rest / 3;
    int d    = cfg + 1;
    int i0   = rowg * 4;

    int t    = threadIdx.x;
    int wv   = t >> 6;
    int lane = t & 63;
    int l15  = lane & 15;
    int quad = lane >> 4;

    // 10 rows (i0-3 .. i0+6, circular) x 64 cols x 32 ch bf16 = 40 KB
    __shared__ __align__(16) unsigned short tile[10 * 2048];
    __shared__ float red_s[4][32];
    __shared__ float red_q[4][32];

    const unsigned short* xTb = xT + (size_t)b * IMG * 32;
#pragma unroll
    for (int rr = 0; rr < 10; rr++) {
        int gi = (i0 - 3 + rr) & 63;
        GLDS(xTb + (size_t)gi * 2048 + t * 8, &tile[rr * 2048 + t * 8]);
    }

    const unsigned short* pwc = pw + (size_t)cfg * 9 * 32 * 32;
    short8 af[2][9];
#pragma unroll
    for (int h = 0; h < 2; h++)
#pragma unroll
        for (int tap = 0; tap < 9; tap++)
            af[h][tap] = *(const short8*)(pwc + ((tap * 32 + h * 16 + l15) * 32 + quad * 8));

    __syncthreads();  // drains GLDS (vmcnt) for all waves

    float ss[2][4], qq[2][4];
#pragma unroll
    for (int h = 0; h < 2; h++)
#pragma unroll
        for (int r = 0; r < 4; r++) { ss[h][r] = 0.f; qq[h][r] = 0.f; }

#pragma unroll 1
    for (int cg = 0; cg < 4; cg++) {
        floatx4 a0 = {0.f, 0.f, 0.f, 0.f};
        floatx4 a1 = {0.f, 0.f, 0.f, 0.f};
#pragma unroll
        for (int du = 0; du < 3; du++) {
            int rowloc = wv + 3 + (du - 1) * d;        // 0..9
            const unsigned short* rbase = &tile[rowloc * 2048 + quad * 8];
#pragma unroll
            for (int dv = 0; dv < 3; dv++) {
                int col = (cg * 16 + l15 + (dv - 1) * d) & 63;
                short8 bf = *(const short8*)(rbase + col * 32);
                a0 = __builtin_amdgcn_mfma_f32_16x16x32_bf16(af[0][du * 3 + dv], bf, a0, 0, 0, 0);
                a1 = __builtin_amdgcn_mfma_f32_16x16x32_bf16(af[1][du * 3 + dv], bf, a1, 0, 0, 0);
            }
        }
#pragma unroll
        for (int r = 0; r < 4; r++) {
            float v0 = a0[r], v1 = a1[r];
            ss[0][r] += v0; qq[0][r] = fmaf(v0, v0, qq[0][r]);
            ss[1][r] += v1; qq[1][r] = fmaf(v1, v1, qq[1][r]);
        }
    }

    // reduce over the 16 column-lanes -> per-oc row sums
#pragma unroll
    for (int h = 0; h < 2; h++)
#pragma unroll
        for (int r = 0; r < 4; r++) {
            float s = ss[h][r], q = qq[h][r];
            for (int m = 1; m < 16; m <<= 1) {
                s += __shfl_xor(s, m, 64);
                q += __shfl_xor(q, m, 64);
            }
            if (l15 == 0) {
                red_s[wv][h * 16 + quad * 4 + r] = s;
                red_q[wv][h * 16 + quad * 4 + r] = q;
            }
        }
    __syncthreads();
    if (t < 32) {
        float S = red_s[0][t] + red_s[1][t] + red_s[2][t] + red_s[3][t];
        psum[(size_t)(cfg * 32 + t) * NPART + b * 16 + rowg] = S;
    } else if (t < 64) {
        int o = t - 32;
        float Q = red_q[0][o] + red_q[1][o] + red_q[2][o] + red_q[3][o];
        psq[(size_t)(cfg * 32 + o) * NPART + b * 16 + rowg] = Q;
    }
}

// ---------------------------------------------------------------------------
// Pass 2: recompute conv, apply BN (scale/shift derived per block from the
// partials, L2-hot) + tanh, write out directly. Same geometry as pass 1.
// ---------------------------------------------------------------------------
__global__ __launch_bounds__(256, 3) void conv_bn_kernel(
    const unsigned short* __restrict__ xT, const unsigned short* __restrict__ pw,
    const float* __restrict__ psum, const float* __restrict__ psq,
    const float* __restrict__ gamma, const float* __restrict__ beta,
    float* __restrict__ out)
{
    int bid  = blockIdx.x;
    int rowg = bid & 15;
    int rest = bid >> 4;
    int cfg  = rest % 3;
    int b    = rest / 3;
    int d    = cfg + 1;
    int i0   = rowg * 4;

    int t    = threadIdx.x;
    int wv   = t >> 6;
    int lane = t & 63;
    int l15  = lane & 15;
    int quad = lane >> 4;

    __shared__ __align__(16) unsigned short tile[10 * 2048];
    __shared__ float sc_a[32], sc_b[32];

    const unsigned short* xTb = xT + (size_t)b * IMG * 32;
#pragma unroll
    for (int rr = 0; rr < 10; rr++) {
        int gi = (i0 - 3 + rr) & 63;
        GLDS(xTb + (size_t)gi * 2048 + t * 8, &tile[rr * 2048 + t * 8]);
    }

    // finalize BN params for this block's 32 channels (redundant per block, L2-hot):
    // thread t: channel chl = t>>3, slice = t&7 covering 32 of the 256 partials.
    {
        int chl   = t >> 3;
        int slice = t & 7;
        const float* ps = psum + (size_t)(cfg * 32 + chl) * NPART + slice * 32;
        const float* pq = psq  + (size_t)(cfg * 32 + chl) * NPART + slice * 32;
        float s = 0.f, q = 0.f;
#pragma unroll
        for (int k = 0; k < 32; k++) { s += ps[k]; q += pq[k]; }
        for (int m = 1; m < 8; m <<= 1) {
            s += __shfl_xor(s, m, 8);
            q += __shfl_xor(q, m, 8);
        }
        if (slice == 0) {
            const float inv_n = 1.0f / (float)NPIX;
            float mean = s * inv_n;
            float var  = q * inv_n - mean * mean;
            float a    = gamma[cfg * 32 + chl] * rsqrtf(var + 1e-5f);
            sc_a[chl] = a;
            sc_b[chl] = beta[cfg * 32 + chl] - mean * a;
        }
    }

    const unsigned short* pwc = pw + (size_t)cfg * 9 * 32 * 32;
    short8 af[2][9];
#pragma unroll
    for (int h = 0; h < 2; h++)
#pragma unroll
        for (int tap = 0; tap < 9; tap++)
            af[h][tap] = *(const short8*)(pwc + ((tap * 32 + h * 16 + l15) * 32 + quad * 8));

    __syncthreads();  // drains GLDS + publishes sc_a/sc_b

    int row = i0 + wv;
    size_t obase = ((size_t)b * COUT + cfg * 32) * IMG + (size_t)row * WH;

#pragma unroll 1
    for (int cg = 0; cg < 4; cg++) {
        floatx4 a0 = {0.f, 0.f, 0.f, 0.f};
        floatx4 a1 = {0.f, 0.f, 0.f, 0.f};
#pragma unroll
        for (int du = 0; du < 3; du++) {
            int rowloc = wv + 3 + (du - 1) * d;
            const unsigned short* rbase = &tile[rowloc * 2048 + quad * 8];
#pragma unroll
            for (int dv = 0; dv < 3; dv++) {
                int col = (cg * 16 + l15 + (dv - 1) * d) & 63;
                short8 bf = *(const short8*)(rbase + col * 32);
                a0 = __builtin_amdgcn_mfma_f32_16x16x32_bf16(af[0][du * 3 + dv], bf, a0, 0, 0, 0);
                a1 = __builtin_amdgcn_mfma_f32_16x16x32_bf16(af[1][du * 3 + dv], bf, a1, 0, 0, 0);
            }
        }
        int colg = cg * 16 + l15;
#pragma unroll
        for (int r = 0; r < 4; r++) {
            int m0 = quad * 4 + r;
            float v0 = fmaf(a0[r], sc_a[m0],      sc_b[m0]);
            float v1 = fmaf(a1[r], sc_a[16 + m0], sc_b[16 + m0]);
            out[obase + (size_t)m0 * IMG + colg]        = fast_tanh(v0);
            out[obase + (size_t)(16 + m0) * IMG + colg] = fast_tanh(v1);
        }
    }
}

extern "C" void kernel_launch(void* const* d_in, const int* in_sizes, int n_in,
                              void* d_out, int out_size, void* d_ws, size_t ws_size,
                              hipStream_t stream) {
    const float* x     = (const float*)d_in[0];
    const float* w     = (const float*)d_in[1];
    // d_in[2] = mask: tap positions known analytically (3x3 dilated, centered at 32)
    const float* gamma = (const float*)d_in[3];
    const float* beta  = (const float*)d_in[4];
    float* out = (float*)d_out;

    // everything transient lives in d_ws — no d_out aliasing anywhere
    unsigned short* xT = (unsigned short*)d_ws;             // 2097152 bf16 (4 MB)
    unsigned short* pw = xT + XTELEMS;                      // 27648 bf16
    float* psum = (float*)(pw + PWELEMS + 32);              // 96*256
    float* psq  = psum + COUT * NPART;                      // 96*256

    prep_kernel<<<256 + (PWELEMS + 255) / 256, 256, 0, stream>>>(x, w, xT, pw);
    conv_stats_kernel<<<768, 256, 0, stream>>>(xT, pw, psum, psq);
    conv_bn_kernel<<<768, 256, 0, stream>>>(xT, pw, psum, psq, gamma, beta, out);
}

// Round 9
// 117.646 us; speedup vs baseline: 1.6254x; 1.0472x over previous
//
#include <hip/hip_runtime.h>
#include <math.h>

// Problem constants
#define BATCH 16
#define CIN 32
#define COUT 96
#define WH 64
#define IMG (WH*WH)              // 4096
#define NPIX (BATCH*IMG)         // 65536 per channel
#define YELEMS (BATCH*COUT*IMG)  // 6291456
#define NPART 256                // partials per channel: 16 b * 16 rowg
#define PWELEMS (3*9*32*32)      // 27648 packed bf16 weights
#define XTELEMS (BATCH*IMG*CIN)  // 2097152 bf16 transposed x

typedef __attribute__((ext_vector_type(8))) short short8;
typedef __attribute__((ext_vector_type(4))) float floatx4;

__device__ __forceinline__ unsigned short f2bf(float f) {
    union { float f; unsigned u; } v; v.f = f;
    unsigned r = v.u + 0x7FFFu + ((v.u >> 16) & 1u);  // RNE
    return (unsigned short)(r >> 16);
}
__device__ __forceinline__ float bf2f(unsigned short u) {
    union { unsigned u; float f; } v; v.u = (unsigned)u << 16; return v.f;
}

#define GLDS(src, dst) __builtin_amdgcn_global_load_lds( \
    (const __attribute__((address_space(1))) void*)(src), \
    (__attribute__((address_space(3))) void*)(dst), 16, 0, 0)

__device__ __forceinline__ float fast_tanh(float xv) {
    float e = __expf(2.0f * xv);
    return fmaf(-2.0f, __builtin_amdgcn_rcpf(e + 1.0f), 1.0f);
}

// ---------------------------------------------------------------------------
// prep: blocks 0..255 transpose x -> xT[b][pix][c] bf16 ; blocks 256.. pack
// weights -> pw[cfg][tap][oc32][c32] bf16. All in d_ws (no aliasing).
// ---------------------------------------------------------------------------
__global__ __launch_bounds__(256) void prep_kernel(
    const float* __restrict__ x, const float* __restrict__ w,
    unsigned short* __restrict__ xT, unsigned short* __restrict__ pw)
{
    int blk = blockIdx.x;
    if (blk < 256) {
        int t   = blk * 256 + threadIdx.x;   // 65536 = 16 b * 4096 pix
        int b   = t >> 12;
        int pix = t & 4095;
        const float* xb = x + (size_t)b * CIN * IMG + pix;
        unsigned packed[16];
#pragma unroll
        for (int c2 = 0; c2 < 16; c2++) {
            unsigned short lo = f2bf(xb[(size_t)(2 * c2) * IMG]);
            unsigned short hi = f2bf(xb[(size_t)(2 * c2 + 1) * IMG]);
            packed[c2] = (unsigned)lo | ((unsigned)hi << 16);
        }
        uint4* dst = (uint4*)(xT + (size_t)t * 32);
#pragma unroll
        for (int k = 0; k < 4; k++)
            dst[k] = make_uint4(packed[4 * k], packed[4 * k + 1],
                                packed[4 * k + 2], packed[4 * k + 3]);
    } else {
        int e = (blk - 256) * 256 + threadIdx.x;
        if (e >= PWELEMS) return;
        int cfg = e / (9 * 1024);
        int rem = e % (9 * 1024);
        int tap = rem >> 10;
        int oc  = (rem >> 5) & 31;
        int c   = rem & 31;
        int d   = cfg + 1;
        int du  = tap / 3, dv = tap % 3;
        size_t idx = (((size_t)(cfg * 32 + oc) * CIN + c) * 65 + (32 + (du - 1) * d)) * 65
                     + (32 + (dv - 1) * d);
        pw[e] = f2bf(w[idx]);
    }
}

// ---------------------------------------------------------------------------
// conv (implicit GEMM, MFMA 16x16x32 bf16) -> y (bf16) + per-block stats.
// grid = 16 b * 3 cfg * 16 rowg = 768 ; block 256 (4 waves) ; 3 blk/CU.
// Block: 32 oc x 4 rows x 64 cols.
// ---------------------------------------------------------------------------
__global__ __launch_bounds__(256, 3) void conv_stats_kernel(
    const unsigned short* __restrict__ xT, const unsigned short* __restrict__ pw,
    unsigned short* __restrict__ yb, float* __restrict__ psum, float* __restrict__ psq)
{
    int bid  = blockIdx.x;
    int rowg = bid & 15;
    int rest = bid >> 4;         // 0..47
    int cfg  = rest % 3;
    int b    = rest / 3;
    int d    = cfg + 1;
    int i0   = rowg * 4;

    int t    = threadIdx.x;
    int wv   = t >> 6;
    int lane = t & 63;
    int l15  = lane & 15;
    int quad = lane >> 4;

    // 10 rows (i0-3 .. i0+6, circular) x 64 cols x 32 ch bf16 = 40 KB
    __shared__ __align__(16) unsigned short tile[10 * 2048];
    __shared__ float red_s[4][32];
    __shared__ float red_q[4][32];

    const unsigned short* xTb = xT + (size_t)b * IMG * 32;
#pragma unroll
    for (int rr = 0; rr < 10; rr++) {
        int gi = (i0 - 3 + rr) & 63;
        GLDS(xTb + (size_t)gi * 2048 + t * 8, &tile[rr * 2048 + t * 8]);
    }

    const unsigned short* pwc = pw + (size_t)cfg * 9 * 32 * 32;
    short8 af[2][9];
#pragma unroll
    for (int h = 0; h < 2; h++)
#pragma unroll
        for (int tap = 0; tap < 9; tap++)
            af[h][tap] = *(const short8*)(pwc + ((tap * 32 + h * 16 + l15) * 32 + quad * 8));

    __syncthreads();  // drains GLDS (vmcnt) for all waves

    float ss[2][4], qq[2][4];
#pragma unroll
    for (int h = 0; h < 2; h++)
#pragma unroll
        for (int r = 0; r < 4; r++) { ss[h][r] = 0.f; qq[h][r] = 0.f; }

    int row = i0 + wv;
    size_t ybase = ((size_t)b * COUT + cfg * 32) * IMG + (size_t)row * WH;

#pragma unroll 1
    for (int cg = 0; cg < 4; cg++) {
        floatx4 a0 = {0.f, 0.f, 0.f, 0.f};
        floatx4 a1 = {0.f, 0.f, 0.f, 0.f};
#pragma unroll
        for (int du = 0; du < 3; du++) {
            int rowloc = wv + 3 + (du - 1) * d;        // 0..9
            const unsigned short* rbase = &tile[rowloc * 2048 + quad * 8];
#pragma unroll
            for (int dv = 0; dv < 3; dv++) {
                int col = (cg * 16 + l15 + (dv - 1) * d) & 63;
                short8 bf = *(const short8*)(rbase + col * 32);
                a0 = __builtin_amdgcn_mfma_f32_16x16x32_bf16(af[0][du * 3 + dv], bf, a0, 0, 0, 0);
                a1 = __builtin_amdgcn_mfma_f32_16x16x32_bf16(af[1][du * 3 + dv], bf, a1, 0, 0, 0);
            }
        }
        int colg = cg * 16 + l15;
#pragma unroll
        for (int r = 0; r < 4; r++) {
            float v0 = a0[r], v1 = a1[r];
            int m0 = quad * 4 + r;
            yb[ybase + (size_t)m0 * IMG + colg]        = f2bf(v0);
            yb[ybase + (size_t)(16 + m0) * IMG + colg] = f2bf(v1);
            ss[0][r] += v0; qq[0][r] = fmaf(v0, v0, qq[0][r]);
            ss[1][r] += v1; qq[1][r] = fmaf(v1, v1, qq[1][r]);
        }
    }

    // reduce over the 16 column-lanes -> per-oc row sums
#pragma unroll
    for (int h = 0; h < 2; h++)
#pragma unroll
        for (int r = 0; r < 4; r++) {
            float s = ss[h][r], q = qq[h][r];
            for (int m = 1; m < 16; m <<= 1) {
                s += __shfl_xor(s, m, 64);
                q += __shfl_xor(q, m, 64);
            }
            if (l15 == 0) {
                red_s[wv][h * 16 + quad * 4 + r] = s;
                red_q[wv][h * 16 + quad * 4 + r] = q;
            }
        }
    __syncthreads();
    if (t < 32) {
        float S = red_s[0][t] + red_s[1][t] + red_s[2][t] + red_s[3][t];
        psum[(size_t)(cfg * 32 + t) * NPART + b * 16 + rowg] = S;
    } else if (t < 64) {
        int o = t - 32;
        float Q = red_q[0][o] + red_q[1][o] + red_q[2][o] + red_q[3][o];
        psq[(size_t)(cfg * 32 + o) * NPART + b * 16 + rowg] = Q;
    }
}

// ---------------------------------------------------------------------------
// fused finalize + BN + tanh: reads bf16 y, writes fp32 out.
// grid = 16*96 = 1536 blocks, block 256; each block owns one (b,ch) image.
// ---------------------------------------------------------------------------
__global__ __launch_bounds__(256) void bn_tanh_kernel(
    const unsigned short* __restrict__ yb, const float* __restrict__ psum,
    const float* __restrict__ psq, const float* __restrict__ gamma,
    const float* __restrict__ beta, float* __restrict__ out)
{
    __shared__ float part[8];
    __shared__ float sc[2];
    int t  = threadIdx.x;
    int ch = blockIdx.x % COUT;

    float s = psum[(size_t)ch * NPART + t];
    float q = psq[(size_t)ch * NPART + t];
    for (int m = 1; m < 64; m <<= 1) {
        s += __shfl_xor(s, m, 64);
        q += __shfl_xor(q, m, 64);
    }
    if ((t & 63) == 0) { part[t >> 6] = s; part[4 + (t >> 6)] = q; }
    __syncthreads();
    if (t == 0) {
        const float inv_n = 1.0f / (float)NPIX;
        float S = part[0] + part[1] + part[2] + part[3];
        float Q = part[4] + part[5] + part[6] + part[7];
        float mean = S * inv_n;
        float var  = Q * inv_n - mean * mean;
        float a    = gamma[ch] * rsqrtf(var + 1e-5f);
        sc[0] = a;
        sc[1] = beta[ch] - mean * a;
    }
    __syncthreads();

    float a = sc[0], bsh = sc[1];
    size_t base = (size_t)blockIdx.x * IMG;
#pragma unroll
    for (int k = 0; k < 2; k++) {
        size_t off = base + k * 2048 + t * 8;          // 8 bf16 per thread
        uint4 raw = *(const uint4*)(yb + off);
        const unsigned short* u = (const unsigned short*)&raw;
        float4 r0, r1;
        r0.x = fast_tanh(fmaf(bf2f(u[0]), a, bsh));
        r0.y = fast_tanh(fmaf(bf2f(u[1]), a, bsh));
        r0.z = fast_tanh(fmaf(bf2f(u[2]), a, bsh));
        r0.w = fast_tanh(fmaf(bf2f(u[3]), a, bsh));
        r1.x = fast_tanh(fmaf(bf2f(u[4]), a, bsh));
        r1.y = fast_tanh(fmaf(bf2f(u[5]), a, bsh));
        r1.z = fast_tanh(fmaf(bf2f(u[6]), a, bsh));
        r1.w = fast_tanh(fmaf(bf2f(u[7]), a, bsh));
        *(float4*)(out + off)     = r0;
        *(float4*)(out + off + 4) = r1;
    }
}

extern "C" void kernel_launch(void* const* d_in, const int* in_sizes, int n_in,
                              void* d_out, int out_size, void* d_ws, size_t ws_size,
                              hipStream_t stream) {
    const float* x     = (const float*)d_in[0];
    const float* w     = (const float*)d_in[1];
    // d_in[2] = mask: tap positions known analytically (3x3 dilated, centered at 32)
    const float* gamma = (const float*)d_in[3];
    const float* beta  = (const float*)d_in[4];
    float* out = (float*)d_out;

    // everything transient in d_ws — no d_out aliasing anywhere
    unsigned short* xT = (unsigned short*)d_ws;             // 2097152 bf16 (4 MB)
    unsigned short* pw = xT + XTELEMS;                      // 27648 bf16
    unsigned short* yb = pw + PWELEMS + 32;                 // 6291456 bf16 (12.6 MB)
    float* psum = (float*)(yb + YELEMS);                    // 96*256
    float* psq  = psum + COUT * NPART;                      // 96*256

    prep_kernel<<<256 + (PWELEMS + 255) / 256, 256, 0, stream>>>(x, w, xT, pw);
    conv_stats_kernel<<<768, 256, 0, stream>>>(xT, pw, yb, psum, psq);
    bn_tanh_kernel<<<BATCH * COUT, 256, 0, stream>>>(yb, psum, psq, gamma, beta, out);
}